// Round 8
// baseline (70.745 us; speedup 1.0000x reference)
//
#include <hip/hip_runtime.h>
#include <math.h>

#define BB 4
#define HH 512
#define WW 512
#define CC 32
#define PADC 3
#define NHK 16   // h chunks of 32 rows
#define NWK 16   // w chunks of 32 cols

typedef float f4nat __attribute__((ext_vector_type(4)));  // NT-load/store-compatible

struct Params {
    int ym, xm, hc, wc, rh, rw, dy, dx;
    float ry, rx;
};

struct FastRec {
    int flag, iLo, iHi, jLo, jHi, dY, dX, pad;
};

// bit = round(sigmoid(v))==1. sigmoid monotone, sigmoid(0)=0.5 (round-half-
// even -> 0), so bit <=> v > 0. (FP-boundary mismatch vs the reference needs
// an entire 512-elem scan column inside (0, 6e-8): prob ~2^-512.)
__device__ __forceinline__ unsigned int pos_bit(float v) { return v > 0.0f ? 1u : 0u; }

// Fused detect+copy. One block per (b,hk,wk) tile: 32 rows x 32 w x 32 c.
// Streams the tile verbatim to out (speculative identity copy, corrected by
// fixfin_kernel), assembles per-w channel masks via 8-lane shuffle-OR,
// ORs over rows in registers -> colpart; per-row wave OR + LDS -> rowpart.
// NT loads+stores: data is consumed exactly once here (identity case).
__global__ __launch_bounds__(256) void scan_kernel(const float* __restrict__ x,
                                                   unsigned int* __restrict__ rowpart,
                                                   unsigned int* __restrict__ colpart,
                                                   float* __restrict__ out) {
    const int blk = blockIdx.x;                 // b(2) | hk(4) | wk(4)
    const int b = blk >> 8;
    const int hk = (blk >> 4) & 15;
    const int wk = blk & 15;
    const int t = threadIdx.x;
    const int c4 = t & 7;                       // f4 index within the 32 channels
    const int wi = t >> 3;                      // 0..31 within the 32-w tile

    __shared__ unsigned int rowbuf[32][4];      // [row][wave]

    // f4 index of (b, hk*32, wk*32 + wi, c4*4)
    size_t f0 = ((size_t)(b * HH + hk * 32) * WW + wk * 32 + wi) * (CC / 4) + c4;
    const f4nat* xin = (const f4nat*)x;
    f4nat* xout = (f4nat*)out;

    unsigned int colacc = 0;
    #pragma unroll 4
    for (int r = 0; r < 32; ++r) {
        size_t idx = f0 + (size_t)r * (WW * CC / 4);
        f4nat v = __builtin_nontemporal_load(xin + idx);
        __builtin_nontemporal_store(v, xout + idx);
        unsigned int nib = pos_bit(v.x) | (pos_bit(v.y) << 1) |
                           (pos_bit(v.z) << 2) | (pos_bit(v.w) << 3);
        unsigned int m = nib << (c4 * 4);
        m |= __shfl_xor(m, 1);
        m |= __shfl_xor(m, 2);
        m |= __shfl_xor(m, 4);                  // full 32-c mask for this w, uniform in 8-group
        colacc |= m;
        unsigned int rm = m;
        rm |= __shfl_xor(rm, 8);
        rm |= __shfl_xor(rm, 16);
        rm |= __shfl_xor(rm, 32);               // OR over the wave's 8 w
        if ((t & 63) == 0) rowbuf[r][t >> 6] = rm;
    }
    if (c4 == 0)                                // one writer per w
        colpart[(size_t)(hk * BB + b) * WW + wk * 32 + wi] = colacc;
    __syncthreads();
    if (t < 32) {
        unsigned int rw = rowbuf[t][0] | rowbuf[t][1] | rowbuf[t][2] | rowbuf[t][3];
        rowpart[(size_t)(wk * BB + b) * HH + hk * 32 + t] = rw;
    }
}

// Merged bbox+fixup. 1024 blocks (256 per batch). Every block redundantly
// reduces the partial masks (L2-resident) and computes Params + FastRec in
// LDS, then runs its fixup slice: identity case -> zero the invalid borders
// only; general case -> full bilinear rewrite of batch b.
__global__ __launch_bounds__(256) void fixfin_kernel(const float* __restrict__ x,
                                                     const unsigned int* __restrict__ rowpart,
                                                     const unsigned int* __restrict__ colpart,
                                                     float* __restrict__ out) {
    const int blk = blockIdx.x;
    const int b = blk >> 8, loc = blk & 255;
    const int t = threadIdx.x;
    __shared__ unsigned int colmask[WW];
    __shared__ unsigned int rowmask[HH];
    for (int u = t; u < WW; u += 256) {
        unsigned int a = 0;
        #pragma unroll
        for (int k = 0; k < NHK; ++k) a |= colpart[(size_t)(k * BB + b) * WW + u];
        colmask[u] = a;
    }
    for (int u = t; u < HH; u += 256) {
        unsigned int a = 0;
        #pragma unroll
        for (int k = 0; k < NWK; ++k) a |= rowpart[(size_t)(k * BB + b) * HH + u];
        rowmask[u] = a;
    }
    __syncthreads();

    __shared__ Params sp[CC];
    __shared__ int ok[CC];
    __shared__ FastRec sf;
    const int g = t >> 5, lane = t & 31;       // 8 groups x 32 lanes
    #pragma unroll
    for (int q = 0; q < 4; ++q) {
        const int c = g * 4 + q;               // each group covers 4 channels
        int fx = WW, lx = -1, fy = HH, ly = -1;
        for (int m = 0; m < WW / 32; ++m) {
            int w = m * 32 + lane;
            if ((colmask[w] >> c) & 1u) { fx = min(fx, w); lx = max(lx, w); }
            if ((rowmask[w] >> c) & 1u) { fy = min(fy, w); ly = max(ly, w); }
        }
        for (int off = 16; off; off >>= 1) {   // stays within the 32-lane group
            fx = min(fx, __shfl_xor(fx, off));
            lx = max(lx, __shfl_xor(lx, off));
            fy = min(fy, __shfl_xor(fy, off));
            ly = max(ly, __shfl_xor(ly, off));
        }
        if (lane == 0) {
            // argmax quirks: no active -> 0; min-side first-active at last index -> 0.
            int xm = (fx <= WW - 2) ? fx : 0;
            int xM = (lx >= 0) ? lx : 0;
            int ym = (fy <= HH - 2) ? fy : 0;
            int yM = (ly >= 0) ? ly : 0;
            int hc = max(yM - ym, 1), wc = max(xM - xm, 1);
            int zh = max(HH - 2 * PADC, hc), zw = max(WW - 2 * PADC, wc);
            float scale = fminf((float)zh / (float)hc, (float)zw / (float)wc);
            int rh = (int)rintf(scale * (float)hc);   // round-half-even = jnp.round
            int rw = (int)rintf(scale * (float)wc);
            int pad_y = max(0, (HH - rh) / 2), crop_y = max(0, (rh - HH) / 2);
            int pad_x = max(0, (WW - rw) / 2), crop_x = max(0, (rw - WW) / 2);
            Params p;
            p.ym = ym; p.xm = xm; p.hc = hc; p.wc = wc; p.rh = rh; p.rw = rw;
            p.dy = pad_y - crop_y; p.dx = pad_x - crop_x;
            p.ry = (float)hc / (float)rh;
            p.rx = (float)wc / (float)rw;
            sp[c] = p;
        }
    }
    __syncthreads();
    if (t < CC) {
        Params p = sp[t];
        const Params& p0 = sp[0];
        bool simple = (p.rh == p.hc) && (p.rw == p.wc);   // => scale ratio exactly 1
        bool same = (p.ym == p0.ym) && (p.xm == p0.xm) && (p.dy == p0.dy) &&
                    (p.dx == p0.dx) && (p.rh == p0.rh) && (p.rw == p0.rw);
        ok[t] = (simple && same) ? 1 : 0;
    }
    __syncthreads();
    if (t == 0) {
        int all = 1;
        for (int k = 0; k < CC; ++k) all &= ok[k];
        Params p0 = sp[0];
        FastRec f;
        f.flag = all;
        f.iLo = p0.dy; f.iHi = p0.dy + p0.rh;
        f.jLo = p0.dx; f.jHi = p0.dx + p0.rw;
        f.dY = p0.ym - p0.dy; f.dX = p0.xm - p0.dx;
        f.pad = 0;
        sf = f;
    }
    __syncthreads();
    FastRec f = sf;

    bool ident = f.flag && f.dY == 0 && f.dX == 0 && f.iLo == 0 && f.jLo == 0;
    if (ident) {
        if (loc >= 32) return;                 // 8192 threads handle the border
        const int rowsZ = HH - f.iHi;          // full zero rows at the bottom
        const int W8 = (WW - f.jHi) * 8;       // f4 per row in right zero strip
        const int rowElems = rowsZ * (WW * CC / 4);      // rowsZ * 4096
        const int total = rowElems + f.iHi * W8;
        for (int u = loc * 256 + t; u < total; u += 8192) {
            size_t q;
            if (u < rowElems) {
                int i = f.iHi + (u >> 12);     // 4096 f4 per row
                int r = u & 4095;
                q = ((size_t)b << 21) | ((size_t)i << 12) | r;
            } else {
                int v = u - rowElems;
                int i = v / W8;
                int r = v - i * W8;
                int j = f.jHi + (r >> 3);
                q = ((size_t)b << 21) | ((size_t)i << 12) | ((size_t)j << 3) | (r & 7);
            }
            __builtin_nontemporal_store((f4nat)0.0f, (f4nat*)out + q);
        }
        return;
    }
    const float* base = x + (size_t)b * ((size_t)HH * WW * CC);
    for (int u = loc * 256 + t; u < HH * WW * CC / 4; u += 65536) {
        const int c0 = (u & 7) * 4;
        const int j = (u >> 3) & 511;
        const int i = u >> 12;
        f4nat r;
        #pragma unroll
        for (int k = 0; k < 4; ++k) {
            Params p = sp[c0 + k];
            int ri = i - p.dy, rj = j - p.dx;
            bool valid = (ri >= 0) && (ri < p.rh) && (rj >= 0) && (rj < p.rw);
            float sy = (float)ri * p.ry;
            float sx = (float)rj * p.rx;
            int y0 = min(max((int)floorf(sy), 0), p.hc - 1);
            int x0 = min(max((int)floorf(sx), 0), p.wc - 1);
            int y1 = min(y0 + 1, p.hc - 1);
            int x1 = min(x0 + 1, p.wc - 1);
            float wy = fminf(fmaxf(sy - (float)y0, 0.0f), 1.0f);
            float wx = fminf(fmaxf(sx - (float)x0, 0.0f), 1.0f);
            int Y0 = min(p.ym + y0, HH - 1);
            int Y1 = min(p.ym + y1, HH - 1);
            int X0 = min(p.xm + x0, WW - 1);
            int X1 = min(p.xm + x1, WW - 1);
            float v00 = base[((size_t)Y0 * WW + X0) * CC + c0 + k];
            float v01 = base[((size_t)Y0 * WW + X1) * CC + c0 + k];
            float v10 = base[((size_t)Y1 * WW + X0) * CC + c0 + k];
            float v11 = base[((size_t)Y1 * WW + X1) * CC + c0 + k];
            float top = v00 * (1.0f - wx) + v01 * wx;
            float bot = v10 * (1.0f - wx) + v11 * wx;
            float o = top * (1.0f - wy) + bot * wy;
            r[k] = valid ? o : 0.0f;
        }
        __builtin_nontemporal_store(r, (f4nat*)out + (((size_t)b << 21) + u));
    }
}

extern "C" void kernel_launch(void* const* d_in, const int* in_sizes, int n_in,
                              void* d_out, int out_size, void* d_ws, size_t ws_size,
                              hipStream_t stream) {
    const float* x = (const float*)d_in[0];
    float* out = (float*)d_out;
    unsigned char* ws = (unsigned char*)d_ws;
    unsigned int* colpart = (unsigned int*)ws;                 // NHK*BB*WW = 128 KiB
    unsigned int* rowpart = (unsigned int*)(ws + 131072);      // NWK*BB*HH = 128 KiB

    hipLaunchKernelGGL(scan_kernel, dim3(BB * NHK * NWK), dim3(256), 0, stream,
                       x, rowpart, colpart, out);
    hipLaunchKernelGGL(fixfin_kernel, dim3(BB * 256), dim3(256), 0, stream,
                       x, rowpart, colpart, out);
}

// Round 9
// 58.224 us; speedup vs baseline: 1.2150x; 1.2150x over previous
//
#include <hip/hip_runtime.h>
#include <math.h>

#define BB 4
#define HH 512
#define WW 512
#define CC 32
#define PADC 3
#define NHK 16   // h chunks of 32 rows
#define NWK 16   // w chunks of 32 cols

typedef float f4nat __attribute__((ext_vector_type(4)));  // NT-store-compatible

struct Params {
    int ym, xm, hc, wc, rh, rw, dy, dx;
    float ry, rx;
};

struct FastRec {
    int flag, iLo, iHi, jLo, jHi, dY, dX, pad;
};

// bit = round(sigmoid(v))==1. sigmoid monotone, sigmoid(0)=0.5 (round-half-
// even -> 0), so bit <=> v > 0. (FP-boundary mismatch vs the reference needs
// an entire 512-elem scan column inside (0, 6e-8): prob ~2^-512.)
__device__ __forceinline__ unsigned int pos_bit(float v) { return v > 0.0f ? 1u : 0u; }

// Fused detect+copy. One block per (b,hk,wk) tile: 32 rows x 32 w x 32 c.
// Streams the tile verbatim to out (speculative identity copy, corrected by
// fixup_kernel), assembles per-w channel masks via 8-lane shuffle-OR,
// ORs over rows in registers -> colpart; per-row wave OR + LDS -> rowpart.
// PLAIN loads (keep input L3-resident across replays: NT loads cost +67 MB
// HBM fetch, measured round 8); NT stores (output is never re-read).
__global__ __launch_bounds__(256) void scan_kernel(const float* __restrict__ x,
                                                   unsigned int* __restrict__ rowpart,
                                                   unsigned int* __restrict__ colpart,
                                                   float* __restrict__ out) {
    const int blk = blockIdx.x;                 // b(2) | hk(4) | wk(4)
    const int b = blk >> 8;
    const int hk = (blk >> 4) & 15;
    const int wk = blk & 15;
    const int t = threadIdx.x;
    const int c4 = t & 7;                       // f4 index within the 32 channels
    const int wi = t >> 3;                      // 0..31 within the 32-w tile

    __shared__ unsigned int rowbuf[32][4];      // [row][wave]

    // f4 index of (b, hk*32, wk*32 + wi, c4*4)
    size_t f0 = ((size_t)(b * HH + hk * 32) * WW + wk * 32 + wi) * (CC / 4) + c4;
    const f4nat* xin = (const f4nat*)x;
    f4nat* xout = (f4nat*)out;

    unsigned int colacc = 0;
    #pragma unroll 4
    for (int r = 0; r < 32; ++r) {
        size_t idx = f0 + (size_t)r * (WW * CC / 4);
        f4nat v = xin[idx];
        __builtin_nontemporal_store(v, xout + idx);
        unsigned int nib = pos_bit(v.x) | (pos_bit(v.y) << 1) |
                           (pos_bit(v.z) << 2) | (pos_bit(v.w) << 3);
        unsigned int m = nib << (c4 * 4);
        m |= __shfl_xor(m, 1);
        m |= __shfl_xor(m, 2);
        m |= __shfl_xor(m, 4);                  // full 32-c mask for this w, uniform in 8-group
        colacc |= m;
        unsigned int rm = m;
        rm |= __shfl_xor(rm, 8);
        rm |= __shfl_xor(rm, 16);
        rm |= __shfl_xor(rm, 32);               // OR over the wave's 8 w
        if ((t & 63) == 0) rowbuf[r][t >> 6] = rm;
    }
    if (c4 == 0)                                // one writer per w
        colpart[(size_t)(hk * BB + b) * WW + wk * 32 + wi] = colacc;
    __syncthreads();
    if (t < 32) {
        unsigned int rw = rowbuf[t][0] | rowbuf[t][1] | rowbuf[t][2] | rowbuf[t][3];
        rowpart[(size_t)(wk * BB + b) * HH + hk * 32 + t] = rw;
    }
}

// One block per b. ORs the 16 col/row partial chunks into LDS masks, then
// per-(c,32-lane) bbox scan + Params + per-b FastRec. Same arithmetic as the
// reference (incl. argmax quirks).
__global__ __launch_bounds__(1024) void bboxfin_kernel(const unsigned int* __restrict__ rowpart,
                                                       const unsigned int* __restrict__ colpart,
                                                       Params* __restrict__ prm,
                                                       FastRec* __restrict__ fast) {
    const int b = blockIdx.x;
    const int t = threadIdx.x;
    __shared__ unsigned int colmask[WW];
    __shared__ unsigned int rowmask[HH];
    if (t < WW) {
        unsigned int a = 0;
        #pragma unroll
        for (int k = 0; k < NHK; ++k) a |= colpart[(size_t)(k * BB + b) * WW + t];
        colmask[t] = a;
    } else {
        const int h = t - WW;
        unsigned int a = 0;
        #pragma unroll
        for (int k = 0; k < NWK; ++k) a |= rowpart[(size_t)(k * BB + b) * HH + h];
        rowmask[h] = a;
    }
    __syncthreads();
    const int c = t >> 5, lane = t & 31;
    int fx = WW, lx = -1, fy = HH, ly = -1;
    for (int m = 0; m < WW / 32; ++m) {
        int w = m * 32 + lane;
        if ((colmask[w] >> c) & 1u) { fx = min(fx, w); lx = max(lx, w); }
        if ((rowmask[w] >> c) & 1u) { fy = min(fy, w); ly = max(ly, w); }
    }
    for (int off = 16; off; off >>= 1) {       // stays within the 32-lane group
        fx = min(fx, __shfl_xor(fx, off));
        lx = max(lx, __shfl_xor(lx, off));
        fy = min(fy, __shfl_xor(fy, off));
        ly = max(ly, __shfl_xor(ly, off));
    }
    __shared__ Params sp[CC];
    __shared__ int ok[CC];
    if (lane == 0) {
        // argmax quirks: no active -> 0; min-side first-active at last index -> 0.
        int xm = (fx <= WW - 2) ? fx : 0;
        int xM = (lx >= 0) ? lx : 0;
        int ym = (fy <= HH - 2) ? fy : 0;
        int yM = (ly >= 0) ? ly : 0;
        int hc = max(yM - ym, 1), wc = max(xM - xm, 1);
        int zh = max(HH - 2 * PADC, hc), zw = max(WW - 2 * PADC, wc);
        float scale = fminf((float)zh / (float)hc, (float)zw / (float)wc);
        int rh = (int)rintf(scale * (float)hc);   // round-half-even = jnp.round
        int rw = (int)rintf(scale * (float)wc);
        int pad_y = max(0, (HH - rh) / 2), crop_y = max(0, (rh - HH) / 2);
        int pad_x = max(0, (WW - rw) / 2), crop_x = max(0, (rw - WW) / 2);
        Params p;
        p.ym = ym; p.xm = xm; p.hc = hc; p.wc = wc; p.rh = rh; p.rw = rw;
        p.dy = pad_y - crop_y; p.dx = pad_x - crop_x;
        p.ry = (float)hc / (float)rh;
        p.rx = (float)wc / (float)rw;
        sp[c] = p;
    }
    __syncthreads();
    if (t < CC) {
        Params p = sp[t];
        const Params& p0 = sp[0];
        bool simple = (p.rh == p.hc) && (p.rw == p.wc);   // => scale ratio exactly 1
        bool same = (p.ym == p0.ym) && (p.xm == p0.xm) && (p.dy == p0.dy) &&
                    (p.dx == p0.dx) && (p.rh == p0.rh) && (p.rw == p0.rw);
        ok[t] = (simple && same) ? 1 : 0;
        prm[b * CC + t] = p;
    }
    __syncthreads();
    if (t == 0) {
        int all = 1;
        for (int k = 0; k < CC; ++k) all &= ok[k];
        Params p0 = sp[0];
        FastRec f;
        f.flag = all;
        f.iLo = p0.dy; f.iHi = p0.dy + p0.rh;
        f.jLo = p0.dx; f.jHi = p0.dx + p0.rw;
        f.dY = p0.ym - p0.dy; f.dX = p0.xm - p0.dx;
        f.pad = 0;
        fast[b] = f;
    }
}

// Corrects the speculative identity copy. Identity case (flag && zero shift
// && zero origin): only zero the invalid borders (tiny). Otherwise: fully
// rewrite batch b with the general bilinear path.
__global__ __launch_bounds__(256) void fixup_kernel(const float* __restrict__ x,
                                                    const Params* __restrict__ prm,
                                                    const FastRec* __restrict__ fast,
                                                    float* __restrict__ out) {
    const int blk = blockIdx.x;                // 1024 blocks; 256 per batch
    const int t = threadIdx.x;
    const int b = blk >> 8, loc = blk & 255;
    FastRec f = fast[b];
    bool ident = f.flag && f.dY == 0 && f.dX == 0 && f.iLo == 0 && f.jLo == 0;
    if (ident) {
        if (loc >= 32) return;                 // 8192 threads handle the border
        const int rowsZ = HH - f.iHi;          // full zero rows at the bottom
        const int W8 = (WW - f.jHi) * 8;       // f4 per row in right zero strip
        const int rowElems = rowsZ * (WW * CC / 4);      // rowsZ * 4096
        const int total = rowElems + f.iHi * W8;
        for (int u = loc * 256 + t; u < total; u += 8192) {
            size_t q;
            if (u < rowElems) {
                int i = f.iHi + (u >> 12);     // 4096 f4 per row
                int r = u & 4095;
                q = ((size_t)b << 21) | ((size_t)i << 12) | r;
            } else {
                int v = u - rowElems;
                int i = v / W8;
                int r = v - i * W8;
                int j = f.jHi + (r >> 3);
                q = ((size_t)b << 21) | ((size_t)i << 12) | ((size_t)j << 3) | (r & 7);
            }
            __builtin_nontemporal_store((f4nat)0.0f, (f4nat*)out + q);
        }
        return;
    }
    __shared__ Params sp[CC];
    {
        const int nw = CC * (int)(sizeof(Params) / 4);
        const int* src = (const int*)(prm + b * CC);
        int* dst = (int*)sp;
        for (int k = t; k < nw; k += 256) dst[k] = src[k];
    }
    __syncthreads();
    const float* base = x + (size_t)b * ((size_t)HH * WW * CC);
    for (int u = loc * 256 + t; u < HH * WW * CC / 4; u += 65536) {
        const int c0 = (u & 7) * 4;
        const int j = (u >> 3) & 511;
        const int i = u >> 12;
        f4nat r;
        #pragma unroll
        for (int k = 0; k < 4; ++k) {
            Params p = sp[c0 + k];
            int ri = i - p.dy, rj = j - p.dx;
            bool valid = (ri >= 0) && (ri < p.rh) && (rj >= 0) && (rj < p.rw);
            float sy = (float)ri * p.ry;
            float sx = (float)rj * p.rx;
            int y0 = min(max((int)floorf(sy), 0), p.hc - 1);
            int x0 = min(max((int)floorf(sx), 0), p.wc - 1);
            int y1 = min(y0 + 1, p.hc - 1);
            int x1 = min(x0 + 1, p.wc - 1);
            float wy = fminf(fmaxf(sy - (float)y0, 0.0f), 1.0f);
            float wx = fminf(fmaxf(sx - (float)x0, 0.0f), 1.0f);
            int Y0 = min(p.ym + y0, HH - 1);
            int Y1 = min(p.ym + y1, HH - 1);
            int X0 = min(p.xm + x0, WW - 1);
            int X1 = min(p.xm + x1, WW - 1);
            float v00 = base[((size_t)Y0 * WW + X0) * CC + c0 + k];
            float v01 = base[((size_t)Y0 * WW + X1) * CC + c0 + k];
            float v10 = base[((size_t)Y1 * WW + X0) * CC + c0 + k];
            float v11 = base[((size_t)Y1 * WW + X1) * CC + c0 + k];
            float top = v00 * (1.0f - wx) + v01 * wx;
            float bot = v10 * (1.0f - wx) + v11 * wx;
            float o = top * (1.0f - wy) + bot * wy;
            r[k] = valid ? o : 0.0f;
        }
        __builtin_nontemporal_store(r, (f4nat*)out + (((size_t)b << 21) + u));
    }
}

extern "C" void kernel_launch(void* const* d_in, const int* in_sizes, int n_in,
                              void* d_out, int out_size, void* d_ws, size_t ws_size,
                              hipStream_t stream) {
    const float* x = (const float*)d_in[0];
    float* out = (float*)d_out;
    unsigned char* ws = (unsigned char*)d_ws;
    unsigned int* colpart = (unsigned int*)ws;                 // NHK*BB*WW = 128 KiB
    unsigned int* rowpart = (unsigned int*)(ws + 131072);      // NWK*BB*HH = 128 KiB
    Params* prm = (Params*)(ws + 262144);                      // 5 KiB
    FastRec* fast = (FastRec*)(ws + 267264);                   // 128 B

    hipLaunchKernelGGL(scan_kernel, dim3(BB * NHK * NWK), dim3(256), 0, stream,
                       x, rowpart, colpart, out);
    hipLaunchKernelGGL(bboxfin_kernel, dim3(BB), dim3(1024), 0, stream,
                       rowpart, colpart, prm, fast);
    hipLaunchKernelGGL(fixup_kernel, dim3(1024), dim3(256), 0, stream,
                       x, prm, fast, out);
}